// Round 1
// baseline (2999.086 us; speedup 1.0000x reference)
//
#include <hip/hip_runtime.h>

// WeightedChildSumTreeLSTMEndtoEnd: BRANCH=8, DEPTH=4, N=4681, B=64, IN_DIM=MEM=256
// STARTS = {0,1,9,73,585}, COUNTS = {1,8,64,512,4096}
//
// Round 0: correctness-first fp32-compute baseline.
//  - All GEMMs: 64x64 output tile / block (256 thr), 4x4 register tile per thread,
//    K-tiles of 32 staged in LDS transposed ([k][m], pad 68) so inner loop uses b128 reads.
//  - Intermediates (c, h, G, h_sum) stored bf16 => workspace ~319 MB, and prepares
//    operands for a future MFMA version.
//  - G = h_child @ Wfh^T computed IN-PLACE over h_prev (each block computes all 256
//    cols of its 64 rows; all global reads of those rows complete before epilogue
//    writes; h_sum kernel runs before on the same stream).

typedef unsigned short u16;
typedef unsigned int u32;

#define PAD 68
#define NNODES 4681

__device__ __forceinline__ float bf2f(u32 lo) { return __uint_as_float(lo << 16); }
__device__ __forceinline__ u16 f2bf(float f) {
    u32 u = __float_as_uint(f);
    return (u16)((u + 0x7fffu + ((u >> 16) & 1u)) >> 16);  // RNE
}
__device__ __forceinline__ float sigm(float x) { return 1.0f / (1.0f + __expf(-x)); }
__device__ __forceinline__ float tanh_(float x) {
    float e = __expf(2.0f * x);
    return 1.0f - 2.0f / (e + 1.0f);  // saturates correctly at +/-1
}

// Load a 64-row x 32-k fp32 tile (row stride 256) into LDS transposed [k][m].
__device__ __forceinline__ void load_tile_f32(float* lds, const float* __restrict__ src, int tid) {
    int m = tid >> 2;
    int k0 = (tid & 3) * 8;
    const float* p = src + (size_t)m * 256 + k0;
    float4 v0 = *(const float4*)p;
    float4 v1 = *(const float4*)(p + 4);
    float* q = lds + m;
    q[(k0 + 0) * PAD] = v0.x; q[(k0 + 1) * PAD] = v0.y;
    q[(k0 + 2) * PAD] = v0.z; q[(k0 + 3) * PAD] = v0.w;
    q[(k0 + 4) * PAD] = v1.x; q[(k0 + 5) * PAD] = v1.y;
    q[(k0 + 6) * PAD] = v1.z; q[(k0 + 7) * PAD] = v1.w;
}
// Same but source is bf16.
__device__ __forceinline__ void load_tile_bf16(float* lds, const u16* src, int tid) {
    int m = tid >> 2;
    int k0 = (tid & 3) * 8;
    const u16* p = src + (size_t)m * 256 + k0;
    uint4 v = *(const uint4*)p;
    float* q = lds + m;
    q[(k0 + 0) * PAD] = bf2f(v.x & 0xffffu); q[(k0 + 1) * PAD] = bf2f(v.x >> 16);
    q[(k0 + 2) * PAD] = bf2f(v.y & 0xffffu); q[(k0 + 3) * PAD] = bf2f(v.y >> 16);
    q[(k0 + 4) * PAD] = bf2f(v.z & 0xffffu); q[(k0 + 5) * PAD] = bf2f(v.z >> 16);
    q[(k0 + 6) * PAD] = bf2f(v.w & 0xffffu); q[(k0 + 7) * PAD] = bf2f(v.w >> 16);
}

template <int NG>
__device__ __forceinline__ void mma_tile(const float* As, const float* Ws,
                                         float acc[][4][4], int tx, int ty) {
#pragma unroll
    for (int kk = 0; kk < 32; kk++) {
        float a[4];
#pragma unroll
        for (int i = 0; i < 4; i++) a[i] = As[kk * PAD + ty * 4 + i];
#pragma unroll
        for (int g = 0; g < NG; g++) {
            float w[4];
#pragma unroll
            for (int j = 0; j < 4; j++) w[j] = Ws[g * (32 * PAD) + kk * PAD + tx * 4 + j];
#pragma unroll
            for (int i = 0; i < 4; i++)
#pragma unroll
                for (int j = 0; j < 4; j++)
                    acc[g][i][j] = fmaf(a[i], w[j], acc[g][i][j]);
        }
    }
}

// ---------------- Leaf stage: iou = X @ Wioux^T + bioux + biouh; c,h ----------------
__global__ __launch_bounds__(256) void k_leaf(
    const float* __restrict__ X, const float* __restrict__ Wioux,
    const float* __restrict__ bioux, const float* __restrict__ biouh,
    u16* __restrict__ Cp, u16* __restrict__ Hp) {
    __shared__ float As[32 * PAD];
    __shared__ float Ws[3][32 * PAD];
    const int tid = threadIdx.x;
    const int tx = tid & 15, ty = tid >> 4;
    const int row0 = blockIdx.x * 64;
    const int mem0 = blockIdx.y * 64;
    float acc[3][4][4] = {};
    for (int kt = 0; kt < 256; kt += 32) {
        load_tile_f32(As, X + (size_t)row0 * 256 + kt, tid);
#pragma unroll
        for (int g = 0; g < 3; g++)
            load_tile_f32(Ws[g], Wioux + ((size_t)g * 256 + mem0) * 256 + kt, tid);
        __syncthreads();
        mma_tile<3>(As, &Ws[0][0], acc, tx, ty);
        __syncthreads();
    }
#pragma unroll
    for (int i = 0; i < 4; i++) {
        int row = row0 + ty * 4 + i;
        u16 cpk[4], hpk[4];
#pragma unroll
        for (int j = 0; j < 4; j++) {
            int mem = mem0 + tx * 4 + j;
            float iv = acc[0][i][j] + bioux[mem] + biouh[mem];
            float ov = acc[1][i][j] + bioux[256 + mem] + biouh[256 + mem];
            float uv = acc[2][i][j] + bioux[512 + mem] + biouh[512 + mem];
            float c = sigm(iv) * tanh_(uv);
            float h = sigm(ov) * tanh_(c);
            cpk[j] = f2bf(c); hpk[j] = f2bf(h);
        }
        size_t o = (size_t)row * 256 + mem0 + tx * 4;
        *(ushort4*)(Cp + o) = *(ushort4*)cpk;
        *(ushort4*)(Hp + o) = *(ushort4*)hpk;
    }
}

// ---------------- G = h_prev @ Wfh^T (raw, no bias), IN-PLACE over h_prev ----------------
__global__ __launch_bounds__(256) void k_g(
    const u16* Hprev, const float* __restrict__ Wfh, u16* Gout) {
    __shared__ float As[32 * PAD];
    __shared__ float Ws[4][32 * PAD];
    const int tid = threadIdx.x;
    const int tx = tid & 15, ty = tid >> 4;
    const int row0 = blockIdx.x * 64;
    float acc[4][4][4] = {};
    for (int kt = 0; kt < 256; kt += 32) {
        load_tile_bf16(As, Hprev + (size_t)row0 * 256 + kt, tid);
#pragma unroll
        for (int g = 0; g < 4; g++)
            load_tile_f32(Ws[g], Wfh + ((size_t)g * 64) * 256 + kt, tid);
        __syncthreads();
        mma_tile<4>(As, &Ws[0][0], acc, tx, ty);
        __syncthreads();
    }
#pragma unroll
    for (int i = 0; i < 4; i++) {
        int row = row0 + ty * 4 + i;
#pragma unroll
        for (int g = 0; g < 4; g++) {
            u16 pk[4];
#pragma unroll
            for (int j = 0; j < 4; j++) pk[j] = f2bf(acc[g][i][j]);
            size_t o = (size_t)row * 256 + g * 64 + tx * 4;
            *(ushort4*)(Gout + o) = *(ushort4*)pk;
        }
    }
}

// ---------------- Main per-level GEMM + fused TreeLSTM epilogue ----------------
__global__ __launch_bounds__(256) void k_main(
    const float* __restrict__ X, const u16* __restrict__ Hsum,
    const u16* __restrict__ G, const u16* __restrict__ Cprev,
    const float* __restrict__ pw,
    const float* __restrict__ Wioux, const float* __restrict__ bioux,
    const float* __restrict__ Wiouh, const float* __restrict__ biouh,
    const float* __restrict__ Wfx, const float* __restrict__ bfx,
    const float* __restrict__ bfh,
    u16* __restrict__ Ccur, u16* __restrict__ Hcur,
    float* __restrict__ outc, float* __restrict__ outh) {
    __shared__ float As[32 * PAD];
    __shared__ float Ws[4][32 * PAD];
    __shared__ float pws[8];
    const int tid = threadIdx.x;
    const int tx = tid & 15, ty = tid >> 4;
    const int lp = blockIdx.x;
    const int mem0 = blockIdx.y * 64;
    if (tid < 8) pws[tid] = pw[lp * 8 + tid];
    float acc[4][4][4] = {};
    // pass 1: X against Wioux (gates 0..2) and Wfx (gate 3)
    for (int kt = 0; kt < 256; kt += 32) {
        load_tile_f32(As, X + ((size_t)lp * 64) * 256 + kt, tid);
#pragma unroll
        for (int g = 0; g < 3; g++)
            load_tile_f32(Ws[g], Wioux + ((size_t)g * 256 + mem0) * 256 + kt, tid);
        load_tile_f32(Ws[3], Wfx + (size_t)mem0 * 256 + kt, tid);
        __syncthreads();
        mma_tile<4>(As, &Ws[0][0], acc, tx, ty);
        __syncthreads();
    }
    // pass 2: Hsum against Wiouh (gates 0..2)
    for (int kt = 0; kt < 256; kt += 32) {
        load_tile_bf16(As, Hsum + ((size_t)lp * 64) * 256 + kt, tid);
#pragma unroll
        for (int g = 0; g < 3; g++)
            load_tile_f32(Ws[g], Wiouh + ((size_t)g * 256 + mem0) * 256 + kt, tid);
        __syncthreads();
        mma_tile<3>(As, &Ws[0][0], acc, tx, ty);
        __syncthreads();
    }
    // epilogue
#pragma unroll
    for (int i = 0; i < 4; i++) {
        int b = ty * 4 + i;
        int row = lp * 64 + b;
        float cacc[4], ovv[4], bff[4];
#pragma unroll
        for (int j = 0; j < 4; j++) {
            int mem = mem0 + tx * 4 + j;
            float iv = acc[0][i][j] + bioux[mem] + biouh[mem];
            float ov = acc[1][i][j] + bioux[256 + mem] + biouh[256 + mem];
            float uv = acc[2][i][j] + bioux[512 + mem] + biouh[512 + mem];
            float fxv = acc[3][i][j] + bfx[mem];
            cacc[j] = sigm(iv) * tanh_(uv);
            ovv[j] = ov;
            bff[j] = bfh[mem] + fxv;
        }
#pragma unroll
        for (int ch = 0; ch < 8; ch++) {
            float p = pws[ch];
            size_t base = (((size_t)lp * 8 + ch) * 64 + b) * 256 + mem0 + tx * 4;
            uint2 gg = *(const uint2*)(G + base);
            uint2 cc2 = *(const uint2*)(Cprev + base);
            float g4[4] = {bf2f(gg.x & 0xffffu), bf2f(gg.x >> 16),
                           bf2f(gg.y & 0xffffu), bf2f(gg.y >> 16)};
            float c4[4] = {bf2f(cc2.x & 0xffffu), bf2f(cc2.x >> 16),
                           bf2f(cc2.y & 0xffffu), bf2f(cc2.y >> 16)};
#pragma unroll
            for (int j = 0; j < 4; j++) {
                float f = sigm(fmaf(p, g4[j], bff[j]));
                cacc[j] = fmaf(f * p, c4[j], cacc[j]);
            }
        }
        u16 cpk[4], hpk[4];
        float hv[4];
#pragma unroll
        for (int j = 0; j < 4; j++) {
            hv[j] = sigm(ovv[j]) * tanh_(cacc[j]);
            cpk[j] = f2bf(cacc[j]); hpk[j] = f2bf(hv[j]);
        }
        size_t o = (size_t)row * 256 + mem0 + tx * 4;
        *(ushort4*)(Ccur + o) = *(ushort4*)cpk;
        *(ushort4*)(Hcur + o) = *(ushort4*)hpk;
        if (outc) {  // only level d==0 (lp==0, row==b)
            size_t oo = (size_t)b * 256 + mem0 + tx * 4;
            float4 c4o = make_float4(cacc[0], cacc[1], cacc[2], cacc[3]);
            float4 h4o = make_float4(hv[0], hv[1], hv[2], hv[3]);
            *(float4*)(outc + oo) = c4o;
            *(float4*)(outh + oo) = h4o;
        }
    }
}

// ---------------- h_sum = sum_j pw_j * h_child_j ----------------
__global__ __launch_bounds__(256) void k_hsum(
    const u16* __restrict__ Hprev, const float* __restrict__ pw,
    u16* __restrict__ Hsum, int cnt) {
    int idx = blockIdx.x * 256 + threadIdx.x;  // one thread per 4 mems
    int total = cnt * 64 * 64;
    if (idx >= total) return;
    int q = idx & 63;
    int b = (idx >> 6) & 63;
    int lp = idx >> 12;
    float s0 = 0.f, s1 = 0.f, s2 = 0.f, s3 = 0.f;
#pragma unroll
    for (int ch = 0; ch < 8; ch++) {
        float p = pw[lp * 8 + ch];
        size_t base = (((size_t)lp * 8 + ch) * 64 + b) * 256 + q * 4;
        uint2 hh = *(const uint2*)(Hprev + base);
        s0 = fmaf(p, bf2f(hh.x & 0xffffu), s0);
        s1 = fmaf(p, bf2f(hh.x >> 16), s1);
        s2 = fmaf(p, bf2f(hh.y & 0xffffu), s2);
        s3 = fmaf(p, bf2f(hh.y >> 16), s3);
    }
    u16 pk[4] = {f2bf(s0), f2bf(s1), f2bf(s2), f2bf(s3)};
    size_t o = ((size_t)lp * 64 + b) * 256 + q * 4;
    *(ushort4*)(Hsum + o) = *(ushort4*)pk;
}

// ---------------- pw gather ----------------
__global__ __launch_bounds__(256) void k_pw(
    const float* __restrict__ prob, float* __restrict__ pw, int s, int cnt) {
    int i = blockIdx.x * 256 + threadIdx.x;
    if (i < cnt * 8) {
        int lp = i >> 3, j = i & 7;
        int par = s + lp;
        pw[i] = prob[(size_t)par * NNODES + (8 * par + 1 + j)];
    }
}

extern "C" void kernel_launch(void* const* d_in, const int* in_sizes, int n_in,
                              void* d_out, int out_size, void* d_ws, size_t ws_size,
                              hipStream_t stream) {
    const float* inputs = (const float*)d_in[0];
    const float* prob   = (const float*)d_in[1];
    const float* Wioux  = (const float*)d_in[2];
    const float* bioux  = (const float*)d_in[3];
    const float* Wiouh  = (const float*)d_in[4];
    const float* biouh  = (const float*)d_in[5];
    const float* Wfx    = (const float*)d_in[6];
    const float* bfx    = (const float*)d_in[7];
    const float* Wfh    = (const float*)d_in[8];
    const float* bfh    = (const float*)d_in[9];
    float* outc = (float*)d_out;
    float* outh = outc + 64 * 256;

    // workspace layout (~319 MB)
    const size_t szA = (size_t)4096 * 64 * 256 * 2;  // 128 MiB (bf16)
    const size_t szB = (size_t)512 * 64 * 256 * 2;   // 16 MiB
    char* p = (char*)d_ws;
    u16* Ac = (u16*)p; p += szA;
    u16* Ah = (u16*)p; p += szA;
    u16* Bc = (u16*)p; p += szB;
    u16* Bh = (u16*)p; p += szB;
    u16* Hs = (u16*)p; p += szB;
    float* pwb = (float*)p; p += (size_t)512 * 8 * 4;

    // leaves: nodes [585, 4681)
    k_leaf<<<dim3(4096, 4), 256, 0, stream>>>(
        inputs + (size_t)585 * 64 * 256, Wioux, bioux, biouh, Ac, Ah);

    const int starts[4] = {0, 1, 9, 73};
    const int counts[4] = {1, 8, 64, 512};
    u16 *pc = Ac, *ph = Ah, *cc = Bc, *chh = Bh;
    for (int d = 3; d >= 0; d--) {
        int s = starts[d], cnt = counts[d];
        k_pw<<<(cnt * 8 + 255) / 256, 256, 0, stream>>>(prob, pwb, s, cnt);
        k_hsum<<<(cnt * 64 * 64 + 255) / 256, 256, 0, stream>>>(ph, pwb, Hs, cnt);
        k_g<<<cnt * 8, 256, 0, stream>>>(ph, Wfh, ph);  // in-place G over h_prev
        k_main<<<dim3(cnt, 4), 256, 0, stream>>>(
            inputs + (size_t)s * 64 * 256, Hs, ph, pc, pwb,
            Wioux, bioux, Wiouh, biouh, Wfx, bfx, bfh,
            cc, chh,
            (d == 0) ? outc : nullptr, (d == 0) ? outh : nullptr);
        u16* t;
        t = pc; pc = cc; cc = t;
        t = ph; ph = chh; chh = t;
    }
}

// Round 2
// 1198.133 us; speedup vs baseline: 2.5031x; 2.5031x over previous
//
#include <hip/hip_runtime.h>

// WeightedChildSumTreeLSTMEndtoEnd: BRANCH=8, DEPTH=4, N=4681, B=64, IN_DIM=MEM=256
// STARTS = {0,1,9,73,585}, COUNTS = {1,8,64,512,4096}
//
// Round 1: bf16 MFMA (v_mfma_f32_16x16x32_bf16) for all GEMMs.
//  - Block = 256 thr = 4 waves; output 64 rows x 64 cols x NG gates.
//  - Wave w owns rows [16w,16w+16); per gate 4 col-tiles of 16.
//  - LDS tiles 64 rows x 64 k bf16, row stride 72 (144 B = 9*16B: aligned b128,
//    2-way bank aliasing only -> free per m136).
//  - A-frag: A[m=lane&15][k=quad*8+j]; B-frag from W[n][k] natural row-major
//    (W is (out,in)) -> D[m][n] = sum_k A[m][k]*W[n][k]. C/D: col=lane&15,
//    row=quad*4+reg (m89-verified mapping).
//  - X (fp32) converted to bf16 in-register during staging; weights converted
//    once to bf16 workspace. c,h,G,h_sum stored bf16.
//  - k_g computes G = h_prev @ Wfh^T IN-PLACE over h_prev (block covers all 256
//    cols of its 64 rows; all global reads precede epilogue writes).

typedef unsigned short u16;
typedef unsigned int u32;
typedef __bf16 bf16x8 __attribute__((ext_vector_type(8)));
typedef float f32x4 __attribute__((ext_vector_type(4)));

#define STR 72  // bf16 elems per LDS row: 64 + 8 pad
#define NNODES 4681

__device__ __forceinline__ float bf2f(u32 lo) { return __uint_as_float(lo << 16); }
__device__ __forceinline__ u16 f2bf(float f) {
    u32 u = __float_as_uint(f);
    return (u16)((u + 0x7fffu + ((u >> 16) & 1u)) >> 16);  // RNE
}
__device__ __forceinline__ float sigm(float x) { return 1.0f / (1.0f + __expf(-x)); }
__device__ __forceinline__ float tanh_(float x) {
    float e = __expf(2.0f * x);
    return 1.0f - 2.0f / (e + 1.0f);
}

// Stage 64 rows x 64 k from bf16 global (row stride 256) into LDS [row][k], stride STR.
__device__ __forceinline__ void stage_bf16(u16* lds, const u16* src, int tid) {
    int row = tid >> 2, c = (tid & 3) * 16;
    const u16* p = src + (size_t)row * 256 + c;
    uint4 v0 = *(const uint4*)p;
    uint4 v1 = *(const uint4*)(p + 8);
    u16* q = lds + row * STR + c;
    *(uint4*)q = v0;
    *(uint4*)(q + 8) = v1;
}
// Same from fp32 global, converting to bf16 in-register.
__device__ __forceinline__ void stage_f32(u16* lds, const float* src, int tid) {
    int row = tid >> 2, c = (tid & 3) * 16;
    const float* p = src + (size_t)row * 256 + c;
    u16 pk[16];
#pragma unroll
    for (int q = 0; q < 4; q++) {
        float4 v = *(const float4*)(p + q * 4);
        pk[q * 4 + 0] = f2bf(v.x);
        pk[q * 4 + 1] = f2bf(v.y);
        pk[q * 4 + 2] = f2bf(v.z);
        pk[q * 4 + 3] = f2bf(v.w);
    }
    u16* q2 = lds + row * STR + c;
    *(uint4*)q2 = *(uint4*)pk;
    *(uint4*)(q2 + 8) = *(uint4*)(pk + 8);
}

// One 32-wide K-sub-step: 1 A-frag + NG*4 B-frags + NG*4 MFMAs per wave.
template <int NG>
__device__ __forceinline__ void mma_ksub(const u16* As, const u16* Ws, int wv, int l,
                                         int s, f32x4 (*acc)[4]) {
    const int colb = l & 15, quad = l >> 4;
    const int ko = s * 32 + quad * 8;
    bf16x8 a = *(const bf16x8*)(As + (wv * 16 + colb) * STR + ko);
#pragma unroll
    for (int g = 0; g < NG; g++)
#pragma unroll
        for (int t = 0; t < 4; t++) {
            bf16x8 b = *(const bf16x8*)(Ws + g * (64 * STR) + (t * 16 + colb) * STR + ko);
            acc[g][t] = __builtin_amdgcn_mfma_f32_16x16x32_bf16(a, b, acc[g][t], 0, 0, 0);
        }
}

// ---------------- weight fp32 -> bf16 conversion (once per call) ----------------
__global__ __launch_bounds__(256) void k_cvtw(
    const float* __restrict__ Wioux, const float* __restrict__ Wiouh,
    const float* __restrict__ Wfx, const float* __restrict__ Wfh,
    u16* __restrict__ out) {
    int i4 = (blockIdx.x * 256 + threadIdx.x) * 4;
    const float* p;
    if (i4 < 196608) p = Wioux + i4;
    else if (i4 < 393216) p = Wiouh + (i4 - 196608);
    else if (i4 < 458752) p = Wfx + (i4 - 393216);
    else p = Wfh + (i4 - 458752);
    float4 v = *(const float4*)p;
    u16 pk[4] = {f2bf(v.x), f2bf(v.y), f2bf(v.z), f2bf(v.w)};
    *(ushort4*)(out + i4) = *(ushort4*)pk;
}

// ---------------- Leaf: iou = X @ Wioux^T + biases; c,h ----------------
__global__ __launch_bounds__(256) void k_leaf(
    const float* __restrict__ X, const u16* __restrict__ Wxb,
    const float* __restrict__ bioux, const float* __restrict__ biouh,
    u16* __restrict__ Cp, u16* __restrict__ Hp) {
    __shared__ u16 As[64 * STR];
    __shared__ u16 Ws[3][64 * STR];
    const int tid = threadIdx.x;
    const int mem0 = blockIdx.x * 64;
    const int row0 = blockIdx.y * 64;
    const int l = tid & 63, wv = tid >> 6;
    f32x4 acc[3][4];
#pragma unroll
    for (int g = 0; g < 3; g++)
#pragma unroll
        for (int t = 0; t < 4; t++) acc[g][t] = (f32x4){0.f, 0.f, 0.f, 0.f};
    for (int kt = 0; kt < 256; kt += 64) {
        stage_f32(As, X + (size_t)row0 * 256 + kt, tid);
#pragma unroll
        for (int g = 0; g < 3; g++)
            stage_bf16(Ws[g], Wxb + ((size_t)g * 256 + mem0) * 256 + kt, tid);
        __syncthreads();
        mma_ksub<3>(As, &Ws[0][0], wv, l, 0, acc);
        mma_ksub<3>(As, &Ws[0][0], wv, l, 1, acc);
        __syncthreads();
    }
    const int colb = l & 15, quad = l >> 4;
#pragma unroll
    for (int t = 0; t < 4; t++) {
        int mem = mem0 + t * 16 + colb;
        float bi = bioux[mem] + biouh[mem];
        float bo = bioux[256 + mem] + biouh[256 + mem];
        float bu = bioux[512 + mem] + biouh[512 + mem];
#pragma unroll
        for (int reg = 0; reg < 4; reg++) {
            int row = row0 + wv * 16 + quad * 4 + reg;
            float c = sigm(acc[0][t][reg] + bi) * tanh_(acc[2][t][reg] + bu);
            float h = sigm(acc[1][t][reg] + bo) * tanh_(c);
            size_t o = (size_t)row * 256 + mem;
            Cp[o] = f2bf(c);
            Hp[o] = f2bf(h);
        }
    }
}

// ---------------- G = h_prev @ Wfh^T (raw), IN-PLACE ----------------
__global__ __launch_bounds__(256) void k_g(
    const u16* Hprev, const u16* __restrict__ Wfhb, u16* Gout) {
    __shared__ u16 As[64 * STR];
    __shared__ u16 Ws[4][64 * STR];
    const int tid = threadIdx.x;
    const int row0 = blockIdx.x * 64;
    const int l = tid & 63, wv = tid >> 6;
    f32x4 acc[4][4];
#pragma unroll
    for (int g = 0; g < 4; g++)
#pragma unroll
        for (int t = 0; t < 4; t++) acc[g][t] = (f32x4){0.f, 0.f, 0.f, 0.f};
    for (int kt = 0; kt < 256; kt += 64) {
        stage_bf16(As, Hprev + (size_t)row0 * 256 + kt, tid);
#pragma unroll
        for (int g = 0; g < 4; g++)
            stage_bf16(Ws[g], Wfhb + ((size_t)g * 64) * 256 + kt, tid);
        __syncthreads();
        mma_ksub<4>(As, &Ws[0][0], wv, l, 0, acc);
        mma_ksub<4>(As, &Ws[0][0], wv, l, 1, acc);
        __syncthreads();
    }
    const int colb = l & 15, quad = l >> 4;
#pragma unroll
    for (int g = 0; g < 4; g++)
#pragma unroll
        for (int t = 0; t < 4; t++) {
            int n = g * 64 + t * 16 + colb;
#pragma unroll
            for (int reg = 0; reg < 4; reg++) {
                int row = row0 + wv * 16 + quad * 4 + reg;
                Gout[(size_t)row * 256 + n] = f2bf(acc[g][t][reg]);
            }
        }
}

// ---------------- Main per-level: 4-gate GEMM + fused TreeLSTM epilogue ----------------
__global__ __launch_bounds__(256) void k_main(
    const float* __restrict__ X, const u16* __restrict__ Hsum,
    const u16* __restrict__ G, const u16* __restrict__ Cprev,
    const float* __restrict__ pw,
    const u16* __restrict__ Wxb, const float* __restrict__ bioux,
    const u16* __restrict__ Whb, const float* __restrict__ biouh,
    const u16* __restrict__ Wfxb, const float* __restrict__ bfx,
    const float* __restrict__ bfh,
    u16* __restrict__ Ccur, u16* __restrict__ Hcur,
    float* __restrict__ outc, float* __restrict__ outh) {
    __shared__ u16 As[64 * STR];
    __shared__ u16 Ws[4][64 * STR];
    __shared__ float pws[8];
    const int tid = threadIdx.x;
    const int mem0 = blockIdx.x * 64;
    const int lp = blockIdx.y;
    const int l = tid & 63, wv = tid >> 6;
    if (tid < 8) pws[tid] = pw[lp * 8 + tid];
    f32x4 acc[4][4];
#pragma unroll
    for (int g = 0; g < 4; g++)
#pragma unroll
        for (int t = 0; t < 4; t++) acc[g][t] = (f32x4){0.f, 0.f, 0.f, 0.f};
    // pass 1: X vs Wioux (g=0..2) and Wfx (g=3)
    for (int kt = 0; kt < 256; kt += 64) {
        stage_f32(As, X + ((size_t)lp * 64) * 256 + kt, tid);
#pragma unroll
        for (int g = 0; g < 3; g++)
            stage_bf16(Ws[g], Wxb + ((size_t)g * 256 + mem0) * 256 + kt, tid);
        stage_bf16(Ws[3], Wfxb + (size_t)mem0 * 256 + kt, tid);
        __syncthreads();
        mma_ksub<4>(As, &Ws[0][0], wv, l, 0, acc);
        mma_ksub<4>(As, &Ws[0][0], wv, l, 1, acc);
        __syncthreads();
    }
    // pass 2: Hsum vs Wiouh (g=0..2)
    for (int kt = 0; kt < 256; kt += 64) {
        stage_bf16(As, Hsum + ((size_t)lp * 64) * 256 + kt, tid);
#pragma unroll
        for (int g = 0; g < 3; g++)
            stage_bf16(Ws[g], Whb + ((size_t)g * 256 + mem0) * 256 + kt, tid);
        __syncthreads();
        mma_ksub<3>(As, &Ws[0][0], wv, l, 0, acc);
        mma_ksub<3>(As, &Ws[0][0], wv, l, 1, acc);
        __syncthreads();
    }
    // epilogue
    const int colb = l & 15, quad = l >> 4;
    float cac[4][4], bff[4][4], ovv[4][4];
#pragma unroll
    for (int t = 0; t < 4; t++) {
        int mem = mem0 + t * 16 + colb;
        float bi = bioux[mem] + biouh[mem];
        float bo = bioux[256 + mem] + biouh[256 + mem];
        float bu = bioux[512 + mem] + biouh[512 + mem];
        float bfv = bfx[mem] + bfh[mem];
#pragma unroll
        for (int reg = 0; reg < 4; reg++) {
            cac[t][reg] = sigm(acc[0][t][reg] + bi) * tanh_(acc[2][t][reg] + bu);
            ovv[t][reg] = acc[1][t][reg] + bo;
            bff[t][reg] = bfv + acc[3][t][reg];
        }
    }
#pragma unroll
    for (int ch = 0; ch < 8; ch++) {
        float p = pws[ch];
        size_t rowbase = ((size_t)(lp * 8 + ch) * 64 + wv * 16 + quad * 4) * 256;
#pragma unroll
        for (int t = 0; t < 4; t++) {
            int mem = mem0 + t * 16 + colb;
#pragma unroll
            for (int reg = 0; reg < 4; reg++) {
                size_t idx = rowbase + (size_t)reg * 256 + mem;
                float gv = bf2f((u32)G[idx]);
                float cp = bf2f((u32)Cprev[idx]);
                float f = sigm(fmaf(p, gv, bff[t][reg]));
                cac[t][reg] = fmaf(f * p, cp, cac[t][reg]);
            }
        }
    }
#pragma unroll
    for (int t = 0; t < 4; t++) {
        int mem = mem0 + t * 16 + colb;
#pragma unroll
        for (int reg = 0; reg < 4; reg++) {
            int rl = wv * 16 + quad * 4 + reg;
            float h = sigm(ovv[t][reg]) * tanh_(cac[t][reg]);
            size_t o = ((size_t)lp * 64 + rl) * 256 + mem;
            Ccur[o] = f2bf(cac[t][reg]);
            Hcur[o] = f2bf(h);
            if (outc) {
                size_t oo = (size_t)rl * 256 + mem;
                outc[oo] = cac[t][reg];
                outh[oo] = h;
            }
        }
    }
}

// ---------------- h_sum = sum_j pw_j * h_child_j ----------------
__global__ __launch_bounds__(256) void k_hsum(
    const u16* __restrict__ Hprev, const float* __restrict__ pw,
    u16* __restrict__ Hsum, int cnt) {
    int idx = blockIdx.x * 256 + threadIdx.x;
    int total = cnt * 64 * 64;
    if (idx >= total) return;
    int q = idx & 63;
    int b = (idx >> 6) & 63;
    int lp = idx >> 12;
    float s0 = 0.f, s1 = 0.f, s2 = 0.f, s3 = 0.f;
#pragma unroll
    for (int ch = 0; ch < 8; ch++) {
        float p = pw[lp * 8 + ch];
        size_t base = (((size_t)lp * 8 + ch) * 64 + b) * 256 + q * 4;
        uint2 hh = *(const uint2*)(Hprev + base);
        s0 = fmaf(p, bf2f(hh.x & 0xffffu), s0);
        s1 = fmaf(p, bf2f(hh.x >> 16), s1);
        s2 = fmaf(p, bf2f(hh.y & 0xffffu), s2);
        s3 = fmaf(p, bf2f(hh.y >> 16), s3);
    }
    u16 pk[4] = {f2bf(s0), f2bf(s1), f2bf(s2), f2bf(s3)};
    size_t o = ((size_t)lp * 64 + b) * 256 + q * 4;
    *(ushort4*)(Hsum + o) = *(ushort4*)pk;
}

// ---------------- pw gather ----------------
__global__ __launch_bounds__(256) void k_pw(
    const float* __restrict__ prob, float* __restrict__ pw, int s, int cnt) {
    int i = blockIdx.x * 256 + threadIdx.x;
    if (i < cnt * 8) {
        int lp = i >> 3, j = i & 7;
        int par = s + lp;
        pw[i] = prob[(size_t)par * NNODES + (8 * par + 1 + j)];
    }
}

extern "C" void kernel_launch(void* const* d_in, const int* in_sizes, int n_in,
                              void* d_out, int out_size, void* d_ws, size_t ws_size,
                              hipStream_t stream) {
    const float* inputs = (const float*)d_in[0];
    const float* prob   = (const float*)d_in[1];
    const float* Wioux  = (const float*)d_in[2];
    const float* bioux  = (const float*)d_in[3];
    const float* Wiouh  = (const float*)d_in[4];
    const float* biouh  = (const float*)d_in[5];
    const float* Wfx    = (const float*)d_in[6];
    const float* bfx    = (const float*)d_in[7];
    const float* Wfh    = (const float*)d_in[8];
    const float* bfh    = (const float*)d_in[9];
    float* outc = (float*)d_out;
    float* outh = outc + 64 * 256;

    // workspace layout (~305 MB + 1 MB weights)
    const size_t szA = (size_t)4096 * 64 * 256 * 2;  // 128 MiB (bf16)
    const size_t szB = (size_t)512 * 64 * 256 * 2;   // 16 MiB
    char* p = (char*)d_ws;
    u16* Ac = (u16*)p; p += szA;
    u16* Ah = (u16*)p; p += szA;
    u16* Bc = (u16*)p; p += szB;
    u16* Bh = (u16*)p; p += szB;
    u16* Hs = (u16*)p; p += szB;
    float* pwb = (float*)p; p += (size_t)512 * 8 * 4;
    u16* Wb = (u16*)p; p += (size_t)524288 * 2;
    u16* Wxb  = Wb;            // 768x256
    u16* Whb  = Wb + 196608;   // 768x256
    u16* Wfxb = Wb + 393216;   // 256x256
    u16* Wfhb = Wb + 458752;   // 256x256

    k_cvtw<<<512, 256, 0, stream>>>(Wioux, Wiouh, Wfx, Wfh, Wb);

    // leaves: nodes [585, 4681)
    k_leaf<<<dim3(4, 4096), 256, 0, stream>>>(
        inputs + (size_t)585 * 64 * 256, Wxb, bioux, biouh, Ac, Ah);

    const int starts[4] = {0, 1, 9, 73};
    const int counts[4] = {1, 8, 64, 512};
    u16 *pc = Ac, *ph = Ah, *cc = Bc, *chh = Bh;
    for (int d = 3; d >= 0; d--) {
        int s = starts[d], cnt = counts[d];
        k_pw<<<(cnt * 8 + 255) / 256, 256, 0, stream>>>(prob, pwb, s, cnt);
        k_hsum<<<(cnt * 64 * 64 + 255) / 256, 256, 0, stream>>>(ph, pwb, Hs, cnt);
        k_g<<<cnt * 8, 256, 0, stream>>>(ph, Wfhb, ph);  // in-place G over h_prev
        k_main<<<dim3(4, cnt), 256, 0, stream>>>(
            inputs + (size_t)s * 64 * 256, Hs, ph, pc, pwb,
            Wxb, bioux, Whb, biouh, Wfxb, bfx, bfh,
            cc, chh,
            (d == 0) ? outc : nullptr, (d == 0) ? outh : nullptr);
        u16* t;
        t = pc; pc = cc; cc = t;
        t = ph; ph = chh; chh = t;
    }
}